// Round 2
// baseline (4753.509 us; speedup 1.0000x reference)
//
#include <hip/hip_runtime.h>
#include <hip/hip_bf16.h>

// ---------------------------------------------------------------------------
// RNN_20572893348005: 2-layer tanh RNN, B=64 T=1024 D=128 H=256, out [B,H,T]
//
// v3: MFMA-engined fused scan. Per chunk:
//   proj0 (K=128): xw0 = x_chunk @ W_ih0^T + b0          (dot2 GEMM, unchanged)
//   fused_scan_mfma: 8 WGs x 512 thr, 8 batches/WG.
//     Wstack = [W_hh0; W_ih1; W_hh1] (768x256 f16) held in VGPRs
//     (8 waves x 96 rows x 256 = 192 VGPRs/wave of A-fragments, loaded once).
//     Per step: B-operand = [h0 | h1] (16 cols: 8 U=h0-batches, 8 V=h1-batches)
//     from XOR-swizzled LDS; 48 mfma_f32_16x16x32_f16 per wave; epilogues:
//       rows   0-255: h0[it]    = tanh(y + xw0[it])       (lanes col<8)
//       rows 256-511: xw1[it-1] = y + b1 -> xw1buf        (lanes col<8)
//       rows 512-767: h1[it-2]  = tanh(y + xw1[it-2])     (lanes col>=8)
//     Same verified lag pipeline as v2, 1 barrier/step.
//   transpose_out: tmp [b][tc][j] f16 -> out [b][j][t] (bf16|f32)
// ---------------------------------------------------------------------------

#define B_ 64
#define T_ 1024
#define D_ 128
#define H_ 256

#define NB 8      // batches per scan workgroup
#define NTILE 6   // 16-row tiles per wave; 8 waves * 96 rows = 768

typedef _Float16 half2_t __attribute__((ext_vector_type(2)));
typedef _Float16 f16x8 __attribute__((ext_vector_type(8)));
typedef float f32x4 __attribute__((ext_vector_type(4)));

__device__ __forceinline__ float bf2f(unsigned short u) {
    union { unsigned int i; float f; } v;
    v.i = ((unsigned int)u) << 16;
    return v.f;
}

__device__ __forceinline__ unsigned int cvt2_bf16_to_f16(unsigned int u) {
    union { float f; unsigned int i; } a, b;
    a.i = u << 16;
    b.i = u & 0xFFFF0000u;
    union { _Float16 h[2]; unsigned int u; } r;
    r.h[0] = (_Float16)a.f;
    r.h[1] = (_Float16)b.f;
    return r.u;
}

__device__ __forceinline__ uint4 cvt8_bf16_to_f16(uint4 v) {
    uint4 r;
    r.x = cvt2_bf16_to_f16(v.x);
    r.y = cvt2_bf16_to_f16(v.y);
    r.z = cvt2_bf16_to_f16(v.z);
    r.w = cvt2_bf16_to_f16(v.w);
    return r;
}

__device__ __forceinline__ float dot2(unsigned int a, unsigned int b, float c) {
    union { unsigned int u; half2_t h; } ua, ub;
    ua.u = a; ub.u = b;
#if defined(__HIP_DEVICE_COMPILE__) && __has_builtin(__builtin_amdgcn_fdot2)
    return __builtin_amdgcn_fdot2(ua.h, ub.h, c, false);
#else
    return c + (float)ua.h.x * (float)ub.h.x + (float)ua.h.y * (float)ub.h.y;
#endif
}

// branch-free tanh: (e^{2x}-1)/(e^{2x}+1) via exp2 + rcp; saturates correctly.
__device__ __forceinline__ float fast_tanh(float x) {
#if defined(__HIP_DEVICE_COMPILE__) && __has_builtin(__builtin_amdgcn_exp2f)
    float e = __builtin_amdgcn_exp2f(x * 2.885390081777927f);
#else
    float e = __expf(2.0f * x);
#endif
#if defined(__HIP_DEVICE_COMPILE__) && __has_builtin(__builtin_amdgcn_rcpf)
    return 1.0f - 2.0f * __builtin_amdgcn_rcpf(e + 1.0f);
#else
    return 1.0f - 2.0f / (e + 1.0f);
#endif
}

// ---- dtype detection ------------------------------------------------------
__global__ void detect_dtype(const unsigned short* __restrict__ w, int* __restrict__ flag) {
    if (threadIdx.x == 0 && blockIdx.x == 0) {
        int f = 0;
        for (int i = 0; i < 512; ++i) {
            unsigned e = (w[i] >> 7) & 0xFF;
            if (e >= 127) f = 1;
        }
        *flag = f;
    }
}

// ---- prep: weights -> f16 (W_ih0 + stacked [hh0;ih1;hh1]), biases, carries -
__global__ void prep_w(const void* __restrict__ wih0, const void* __restrict__ whh0,
                       const void* __restrict__ bih0, const void* __restrict__ bhh0,
                       const void* __restrict__ wih1, const void* __restrict__ whh1,
                       const void* __restrict__ bih1, const void* __restrict__ bhh1,
                       _Float16* __restrict__ owih0, _Float16* __restrict__ owstack,
                       float* __restrict__ obias0, float* __restrict__ obias1,
                       uint4* __restrict__ carries, const int* __restrict__ flag) {
    const bool f32 = (*flag != 0);
    int i = blockIdx.x * 256 + threadIdx.x;
    auto rd = [&](const void* p, int idx) -> float {
        return f32 ? ((const float*)p)[idx] : bf2f(((const unsigned short*)p)[idx]);
    };
    if (i < H_ * D_) owih0[i] = (_Float16)rd(wih0, i);
    if (i < H_ * H_) {
        owstack[i]               = (_Float16)rd(whh0, i);  // rows   0-255
        owstack[H_ * H_ + i]     = (_Float16)rd(wih1, i);  // rows 256-511
        owstack[2 * H_ * H_ + i] = (_Float16)rd(whh1, i);  // rows 512-767
    }
    if (i < H_) {
        obias0[i] = rd(bih0, i) + rd(bhh0, i);
        obias1[i] = rd(bih1, i) + rd(bhh1, i);
    }
    if (i < (2 * B_ * H_) / 8) carries[i] = uint4{0, 0, 0, 0};
}

// ---- chunk projection: xw[m][j] = A_row(m) . W[j] + bias[j] --------------
template <int K, bool SRCX>
__global__ __launch_bounds__(256, 1) void proj_chunk(const void* __restrict__ A,
                                                     const _Float16* __restrict__ W,
                                                     const float* __restrict__ bias,
                                                     _Float16* __restrict__ outx,
                                                     const int* __restrict__ flag,
                                                     int t0, int Tc) {
    constexpr int KW = K / 8;  // uint4 (8 f16) per row
    const int j = threadIdx.x;
    const long m0 = (long)blockIdx.x * 16;
    const bool f32 = SRCX && (*flag != 0);

    long arow0;
    if (SRCX) {
        long b = m0 / Tc;
        long tc0 = m0 - b * Tc;
        arow0 = (b * T_ + t0 + tc0) * (long)K;
    } else {
        arow0 = m0 * (long)K;
    }

    uint4 w[KW];
    const uint4* wp = (const uint4*)(W + (long)j * K);
#pragma unroll
    for (int i = 0; i < KW; ++i) w[i] = wp[i];

    __shared__ uint4 xt[16 * KW];
    for (int i = threadIdx.x; i < 16 * KW; i += 256) {
        int r = i / KW, c = i % KW;
        long off = arow0 + (long)r * K + (long)c * 8;  // element offset
        if (SRCX) {
            if (f32) {
                const float* s = (const float*)A + off;
                union { _Float16 h[8]; uint4 u; } r8;
#pragma unroll
                for (int q = 0; q < 8; ++q) r8.h[q] = (_Float16)s[q];
                xt[i] = r8.u;
            } else {
                xt[i] = cvt8_bf16_to_f16(*(const uint4*)((const unsigned short*)A + off));
            }
        } else {
            xt[i] = *(const uint4*)((const _Float16*)A + off);
        }
    }
    __syncthreads();

    const float bb = bias[j];
#pragma unroll 1
    for (int r = 0; r < 16; ++r) {
        const uint4* xr = xt + r * KW;
        float a0 = 0.f, a1 = 0.f, a2 = 0.f, a3 = 0.f;
#pragma unroll
        for (int i = 0; i < KW; ++i) {
            uint4 h = xr[i];   // wave-uniform LDS broadcast
            uint4 ww = w[i];
            a0 = dot2(ww.x, h.x, a0);
            a1 = dot2(ww.y, h.y, a1);
            a2 = dot2(ww.z, h.z, a2);
            a3 = dot2(ww.w, h.w, a3);
        }
        outx[(m0 + r) * H_ + j] = (_Float16)(((a0 + a1) + (a2 + a3)) + bb);
    }
}

// ---- fused two-layer scan, MFMA-engined ----------------------------------
// 8 WGs x 512 threads (8 waves, 2 waves/SIMD). Wave wv owns Wstack rows
// [96*wv, 96*wv+96) as A-fragments in VGPRs. B-operand rows (LDS, per WG):
// 0-7 = h0 batches (U), 8-15 = h1 batches (V); 512B rows, 16B slots
// XOR-swizzled by (row&7) against bank conflicts.
// Fragment layout (mfma_f32_16x16x32_f16):
//   A: lane holds A[lane&15][8*(lane>>4)+i], i=0..7 (contiguous K)
//   B: lane holds B[8*(lane>>4)+i][lane&15]
//   D: lane holds D[4*(lane>>4)+r][lane&15], r=0..3
__global__ __launch_bounds__(512, 2) void fused_scan_mfma(
    const _Float16* __restrict__ xw0,   // [B][Tc][H] f16 (bias0 included)
    const _Float16* __restrict__ Wst,   // [768][256] f16
    const float* __restrict__ bias1,    // [256] f32
    _Float16* __restrict__ carry0,      // [B][H]
    _Float16* __restrict__ carry1,      // [B][H]
    _Float16* __restrict__ tmp,         // [B][Tc][H] f16 (h1 chunk)
    int Tc)
{
    const int tid  = threadIdx.x;
    const int wv   = tid >> 6;
    const int lane = tid & 63;
    const int col  = lane & 15;
    const int g    = lane >> 4;
    const int b0   = blockIdx.x * NB;
    const int R0   = wv * (NTILE * 16);

    // ---- A fragments: 6 tiles x 8 k-slices x 16B = 192 VGPRs, loaded once
    f16x8 A[NTILE][8];
#pragma unroll
    for (int t = 0; t < NTILE; ++t)
#pragma unroll
        for (int ks = 0; ks < 8; ++ks)
            A[t][ks] = *(const f16x8*)(Wst + (long)(R0 + t * 16 + col) * H_ + ks * 32 + g * 8);

    __shared__ __align__(16) _Float16 Bbuf[2][16][256]; // 512B rows, swizzled slots
    __shared__ __align__(16) float xw1buf[2][NB][260];  // f32, padded rows

    // ---- init: Bbuf[0] = [carry0 | carry1], Bbuf[1] = 0
    {
        const int rr = tid >> 5, s = tid & 31;          // 16 rows x 32 slots
        const int k0 = s * 8;
        const _Float16* src = (rr < NB) ? (carry0 + (long)(b0 + rr) * H_ + k0)
                                        : (carry1 + (long)(b0 + rr - NB) * H_ + k0);
        uint4 v = *(const uint4*)src;
        const int ss = s ^ (rr & 7);
        char* base = (char*)Bbuf;
        *(uint4*)(base + (0 * 16 + rr) * 512 + (ss << 4)) = v;
        *(uint4*)(base + (1 * 16 + rr) * 512 + (ss << 4)) = uint4{0, 0, 0, 0};
    }
    __syncthreads();

#pragma unroll 1
    for (int it = 0; it < Tc + 2; ++it) {
        const int p = it & 1;

        // ---- per-tile operand prefetch (consumed in epilogue):
        //   h0-tile : 8B of xw0[it]      (global, L2-hot)
        //   xw1-tile: 16B of bias1       (global, L1/L2-hot)
        //   h1-tile : 16B of xw1[it-2]   (LDS)
        uint4 pre[NTILE];
#pragma unroll
        for (int tt = 0; tt < NTILE; ++tt) {
            const int RT = R0 + tt * 16;
            if (RT < 256) {
                if (it < Tc) {
                    const int cb = (col < NB) ? col : (NB - 1);
                    const _Float16* s =
                        xw0 + ((long)(b0 + cb) * Tc + it) * H_ + RT + 4 * g;
                    *(uint2*)&pre[tt] = *(const uint2*)s;
                }
            } else if (RT < 512) {
                pre[tt] = *(const uint4*)(bias1 + (RT - 256) + 4 * g);
            } else {
                const int c = (col >= NB) ? (col - NB) : 0;
                pre[tt] = *(const uint4*)&xw1buf[p][c][(RT - 512) + 4 * g];
            }
        }

        // ---- MFMA block: ks-outer (B-frag transient), acc per tile
        f32x4 acc[NTILE];
#pragma unroll
        for (int t = 0; t < NTILE; ++t) acc[t] = (f32x4){0.f, 0.f, 0.f, 0.f};
#pragma unroll
        for (int ks = 0; ks < 8; ++ks) {
            const int slot = ks * 4 + g;
            f16x8 bf = *(const f16x8*)((const char*)Bbuf + (p * 16 + col) * 512 +
                                       ((slot ^ (col & 7)) << 4));
#pragma unroll
            for (int t = 0; t < NTILE; ++t)
                acc[t] = __builtin_amdgcn_mfma_f32_16x16x32_f16(A[t][ks], bf, acc[t], 0, 0, 0);
        }

        // ---- epilogues, h1-tiles first (their global stores retire early)
        char* wbase = (char*)Bbuf + ((p ^ 1) * 16 + col) * 512;
#pragma unroll
        for (int tt = NTILE - 1; tt >= 0; --tt) {
            const int RT = R0 + tt * 16;
            if (RT >= 512) {
                // h1[it-2] = tanh(y_hh1 + xw1[it-2])
                if (it >= 2 && it <= Tc + 1 && col >= NB) {
                    const int c = col - NB;
                    const int j0 = (RT - 512) + 4 * g;
                    union { uint4 u; float f[4]; } xw; xw.u = pre[tt];
                    union { _Float16 h4[4]; uint2 u; } pk;
#pragma unroll
                    for (int r = 0; r < 4; ++r)
                        pk.h4[r] = (_Float16)fast_tanh(acc[tt][r] + xw.f[r]);
                    const int slot = j0 >> 3;
                    *(uint2*)(wbase + ((slot ^ (col & 7)) << 4) + ((j0 * 2) & 15)) = pk.u;
                    *(uint2*)(tmp + ((long)(b0 + c) * Tc + (it - 2)) * H_ + j0) = pk.u;
                    if (it == Tc + 1)
                        *(uint2*)(carry1 + (long)(b0 + c) * H_ + j0) = pk.u;
                }
            } else if (RT >= 256) {
                // xw1[it-1] = y_ih1 + b1
                if (it >= 1 && it <= Tc && col < NB) {
                    const int j0 = (RT - 256) + 4 * g;
                    union { uint4 u; float f[4]; } bv; bv.u = pre[tt];
                    f32x4 v;
#pragma unroll
                    for (int r = 0; r < 4; ++r) v[r] = acc[tt][r] + bv.f[r];
                    *(f32x4*)&xw1buf[p ^ 1][col][j0] = v;
                }
            } else {
                // h0[it] = tanh(y_hh0 + xw0[it])
                if (it < Tc && col < NB) {
                    const int j0 = RT + 4 * g;
                    union { uint2 u; _Float16 h4[4]; } xw; xw.u = *(uint2*)&pre[tt];
                    union { _Float16 h4[4]; uint2 u; } pk;
#pragma unroll
                    for (int r = 0; r < 4; ++r)
                        pk.h4[r] = (_Float16)fast_tanh(acc[tt][r] + (float)xw.h4[r]);
                    const int slot = j0 >> 3;
                    *(uint2*)(wbase + ((slot ^ (col & 7)) << 4) + ((j0 * 2) & 15)) = pk.u;
                    if (it == Tc - 1)
                        *(uint2*)(carry0 + (long)(b0 + col) * H_ + j0) = pk.u;
                }
            }
        }
        __syncthreads();
    }
}

// ---- transpose: tmp [b][tc][j] f16 -> out [b][j][t0+tc] (bf16|f32) -------
__global__ __launch_bounds__(256, 1) void transpose_out(
    const _Float16* __restrict__ tmp, void* __restrict__ out,
    const int* __restrict__ flag, int t0, int Tc)
{
    const int nTc = (Tc + 63) >> 6;
    int bid = blockIdx.x;
    const int jblk = bid & 3; bid >>= 2;           // H_/64 == 4
    const int tcblk = bid % nTc;
    const int b = bid / nTc;
    const bool f32o = (*flag != 0);
    const int tid = threadIdx.x;

    __shared__ float tile[64][65];                 // 65: conflict-free both axes
#pragma unroll
    for (int k = 0; k < 16; ++k) {
        int idx = k * 256 + tid;
        int r = idx >> 6, c = idx & 63;
        int tc = tcblk * 64 + r;
        tile[r][c] = (tc < Tc)
            ? (float)tmp[((long)b * Tc + tc) * H_ + jblk * 64 + c] : 0.f;
    }
    __syncthreads();
#pragma unroll
    for (int k = 0; k < 16; ++k) {
        int idx = k * 256 + tid;
        int jr = idx >> 6, tc = idx & 63;
        if (tcblk * 64 + tc < Tc) {
            float v = tile[tc][jr];
            long o = ((long)b * H_ + jblk * 64 + jr) * (long)T_ + t0 + tcblk * 64 + tc;
            if (f32o) ((float*)out)[o] = v;
            else      ((__hip_bfloat16*)out)[o] = __float2bfloat16(v);
        }
    }
}

// ---------------------------------------------------------------------------
extern "C" void kernel_launch(void* const* d_in, const int* in_sizes, int n_in,
                              void* d_out, int out_size, void* d_ws, size_t ws_size,
                              hipStream_t stream) {
    const void* x    = d_in[0];
    const void* wih0 = d_in[1];
    const void* whh0 = d_in[2];
    const void* bih0 = d_in[3];
    const void* bhh0 = d_in[4];
    const void* wih1 = d_in[5];
    const void* whh1 = d_in[6];
    const void* bih1 = d_in[7];
    const void* bhh1 = d_in[8];
    (void)in_sizes; (void)n_in; (void)out_size;

    char* ws = (char*)d_ws;
    size_t off = 0;
    auto alloc = [&](size_t bytes) -> void* {
        void* p = ws + off;
        off += (bytes + 255) & ~(size_t)255;
        return p;
    };

    int*      flag    = (int*)alloc(256);
    _Float16* wih0_16 = (_Float16*)alloc((size_t)H_ * D_ * 2);
    _Float16* wstack  = (_Float16*)alloc((size_t)3 * H_ * H_ * 2);
    float*    bias0   = (float*)alloc(H_ * 4);
    float*    bias1   = (float*)alloc(H_ * 4);
    _Float16* carry0  = (_Float16*)alloc((size_t)B_ * H_ * 2);
    _Float16* carry1  = (_Float16*)alloc((size_t)B_ * H_ * 2);
    size_t fixed = off;

    // largest chunk Tc (<=256) whose two chunk buffers (xw0 + h1 tmp) fit
    int Tc = 256;
    while (Tc > 16 && fixed + 2 * ((size_t)B_ * Tc * H_ * 2 + 256) > ws_size) Tc >>= 1;
    _Float16* xwc  = (_Float16*)alloc((size_t)B_ * Tc * H_ * 2);
    _Float16* tmpc = (_Float16*)alloc((size_t)B_ * Tc * H_ * 2);

    detect_dtype<<<1, 64, 0, stream>>>((const unsigned short*)whh0, flag);
    prep_w<<<(H_ * H_ + 255) / 256, 256, 0, stream>>>(
        wih0, whh0, bih0, bhh0, wih1, whh1, bih1, bhh1,
        wih0_16, wstack, bias0, bias1, (uint4*)carry0, flag);

    const int nproj = (B_ * Tc) / 16;
    const int nTc   = (Tc + 63) / 64;
    for (int t0 = 0; t0 < T_; t0 += Tc) {
        proj_chunk<D_, true><<<nproj, 256, 0, stream>>>(x, wih0_16, bias0, xwc, flag, t0, Tc);
        fused_scan_mfma<<<B_ / NB, 512, 0, stream>>>(xwc, wstack, bias1,
                                                     carry0, carry1, tmpc, Tc);
        transpose_out<<<B_ * nTc * (H_ / 64), 256, 0, stream>>>(tmpc, d_out, flag, t0, Tc);
    }
}

// Round 3
// 3280.195 us; speedup vs baseline: 1.4492x; 1.4492x over previous
//
#include <hip/hip_runtime.h>
#include <hip/hip_bf16.h>

// ---------------------------------------------------------------------------
// RNN_20572893348005: 2-layer tanh RNN, B=64 T=1024 D=128 H=256, out [B,H,T]
//
// v4: split-layer MFMA scans (v1 chunk structure, MFMA recurrence engine).
// Per chunk:
//   proj0 (K=128): xw0 = x_chunk @ W_ih0^T + b0          (dot2 GEMM, proven)
//   scan_mfma(W_hh0): h0c = scan(xw0)                    (MFMA, 4 WGs)
//   proj1 (K=256): xw1 = h0c @ W_ih1^T + b1              (dot2 GEMM, proven)
//   scan_mfma(W_hh1): h1 -> h0c (reused)                 (MFMA, 4 WGs)
//   transpose_out: h0c [b][tc][j] -> out [b][j][t]
//
// scan_mfma: NB=16 batches/WG (all 16 MFMA B-cols useful), 512 thr = 8 waves,
// NTILE=2 (32 weight rows/wave) -> A-frags = 64 VGPRs, ~110 total (cap 256
// at 2 waves/SIMD): no spill, unlike v3's 250-reg/NTILE=6 layout that went
// to scratch (VGPR_Count=128, 10.6k cy/step). Fragment layouts identical to
// v3 (correctness-validated). One barrier/step; global h-store delayed one
// step so it retires under the next MFMA block.
// ---------------------------------------------------------------------------

#define B_ 64
#define T_ 1024
#define D_ 128
#define H_ 256

#define NB 16     // batches per scan workgroup -> 4 WGs
#define NTILE 2   // 16-row tiles per wave; 8 waves * 32 rows = 256

typedef _Float16 half2_t __attribute__((ext_vector_type(2)));
typedef _Float16 f16x8 __attribute__((ext_vector_type(8)));
typedef float f32x4 __attribute__((ext_vector_type(4)));

__device__ __forceinline__ float bf2f(unsigned short u) {
    union { unsigned int i; float f; } v;
    v.i = ((unsigned int)u) << 16;
    return v.f;
}

__device__ __forceinline__ unsigned int cvt2_bf16_to_f16(unsigned int u) {
    union { float f; unsigned int i; } a, b;
    a.i = u << 16;
    b.i = u & 0xFFFF0000u;
    union { _Float16 h[2]; unsigned int u; } r;
    r.h[0] = (_Float16)a.f;
    r.h[1] = (_Float16)b.f;
    return r.u;
}

__device__ __forceinline__ uint4 cvt8_bf16_to_f16(uint4 v) {
    uint4 r;
    r.x = cvt2_bf16_to_f16(v.x);
    r.y = cvt2_bf16_to_f16(v.y);
    r.z = cvt2_bf16_to_f16(v.z);
    r.w = cvt2_bf16_to_f16(v.w);
    return r;
}

__device__ __forceinline__ float dot2(unsigned int a, unsigned int b, float c) {
    union { unsigned int u; half2_t h; } ua, ub;
    ua.u = a; ub.u = b;
#if defined(__HIP_DEVICE_COMPILE__) && __has_builtin(__builtin_amdgcn_fdot2)
    return __builtin_amdgcn_fdot2(ua.h, ub.h, c, false);
#else
    return c + (float)ua.h.x * (float)ub.h.x + (float)ua.h.y * (float)ub.h.y;
#endif
}

// branch-free tanh: (e^{2x}-1)/(e^{2x}+1) via exp2 + rcp; saturates correctly.
__device__ __forceinline__ float fast_tanh(float x) {
#if defined(__HIP_DEVICE_COMPILE__) && __has_builtin(__builtin_amdgcn_exp2f)
    float e = __builtin_amdgcn_exp2f(x * 2.885390081777927f);
#else
    float e = __expf(2.0f * x);
#endif
#if defined(__HIP_DEVICE_COMPILE__) && __has_builtin(__builtin_amdgcn_rcpf)
    return 1.0f - 2.0f * __builtin_amdgcn_rcpf(e + 1.0f);
#else
    return 1.0f - 2.0f / (e + 1.0f);
#endif
}

// ---- dtype detection ------------------------------------------------------
__global__ void detect_dtype(const unsigned short* __restrict__ w, int* __restrict__ flag) {
    if (threadIdx.x == 0 && blockIdx.x == 0) {
        int f = 0;
        for (int i = 0; i < 512; ++i) {
            unsigned e = (w[i] >> 7) & 0xFF;
            if (e >= 127) f = 1;
        }
        *flag = f;
    }
}

// ---- prep: weights (bf16|f32) -> f16, bias sums -> f32, zero carries -----
__global__ void prep_w(const void* __restrict__ wih0, const void* __restrict__ whh0,
                       const void* __restrict__ bih0, const void* __restrict__ bhh0,
                       const void* __restrict__ wih1, const void* __restrict__ whh1,
                       const void* __restrict__ bih1, const void* __restrict__ bhh1,
                       _Float16* __restrict__ owih0, _Float16* __restrict__ owhh0,
                       _Float16* __restrict__ owih1, _Float16* __restrict__ owhh1,
                       float* __restrict__ obias0, float* __restrict__ obias1,
                       uint4* __restrict__ carries, const int* __restrict__ flag) {
    const bool f32 = (*flag != 0);
    int i = blockIdx.x * 256 + threadIdx.x;
    auto rd = [&](const void* p, int idx) -> float {
        return f32 ? ((const float*)p)[idx] : bf2f(((const unsigned short*)p)[idx]);
    };
    if (i < H_ * D_) owih0[i] = (_Float16)rd(wih0, i);
    if (i < H_ * H_) {
        owhh0[i] = (_Float16)rd(whh0, i);
        owih1[i] = (_Float16)rd(wih1, i);
        owhh1[i] = (_Float16)rd(whh1, i);
    }
    if (i < H_) {
        obias0[i] = rd(bih0, i) + rd(bhh0, i);
        obias1[i] = rd(bih1, i) + rd(bhh1, i);
    }
    if (i < (2 * B_ * H_) / 8) carries[i] = uint4{0, 0, 0, 0};
}

// ---- chunk projection: xw[m][j] = A_row(m) . W[j] + bias[j] --------------
template <int K, bool SRCX>
__global__ __launch_bounds__(256, 1) void proj_chunk(const void* __restrict__ A,
                                                     const _Float16* __restrict__ W,
                                                     const float* __restrict__ bias,
                                                     _Float16* __restrict__ outx,
                                                     const int* __restrict__ flag,
                                                     int t0, int Tc) {
    constexpr int KW = K / 8;  // uint4 (8 f16) per row
    const int j = threadIdx.x;
    const long m0 = (long)blockIdx.x * 16;
    const bool f32 = SRCX && (*flag != 0);

    long arow0;
    if (SRCX) {
        long b = m0 / Tc;
        long tc0 = m0 - b * Tc;
        arow0 = (b * T_ + t0 + tc0) * (long)K;
    } else {
        arow0 = m0 * (long)K;
    }

    uint4 w[KW];
    const uint4* wp = (const uint4*)(W + (long)j * K);
#pragma unroll
    for (int i = 0; i < KW; ++i) w[i] = wp[i];

    __shared__ uint4 xt[16 * KW];
    for (int i = threadIdx.x; i < 16 * KW; i += 256) {
        int r = i / KW, c = i % KW;
        long off = arow0 + (long)r * K + (long)c * 8;  // element offset
        if (SRCX) {
            if (f32) {
                const float* s = (const float*)A + off;
                union { _Float16 h[8]; uint4 u; } r8;
#pragma unroll
                for (int q = 0; q < 8; ++q) r8.h[q] = (_Float16)s[q];
                xt[i] = r8.u;
            } else {
                xt[i] = cvt8_bf16_to_f16(*(const uint4*)((const unsigned short*)A + off));
            }
        } else {
            xt[i] = *(const uint4*)((const _Float16*)A + off);
        }
    }
    __syncthreads();

    const float bb = bias[j];
#pragma unroll 1
    for (int r = 0; r < 16; ++r) {
        const uint4* xr = xt + r * KW;
        float a0 = 0.f, a1 = 0.f, a2 = 0.f, a3 = 0.f;
#pragma unroll
        for (int i = 0; i < KW; ++i) {
            uint4 h = xr[i];   // wave-uniform LDS broadcast
            uint4 ww = w[i];
            a0 = dot2(ww.x, h.x, a0);
            a1 = dot2(ww.y, h.y, a1);
            a2 = dot2(ww.z, h.z, a2);
            a3 = dot2(ww.w, h.w, a3);
        }
        outx[(m0 + r) * H_ + j] = (_Float16)(((a0 + a1) + (a2 + a3)) + bb);
    }
}

// ---- MFMA recurrence scan: h[t] = tanh(W h[t-1] + xw[t]) -----------------
// 4 WGs x 512 thr (8 waves, 2/SIMD). Wave wv owns W rows [32wv, 32wv+32)
// as A-fragments in VGPRs (64 regs). B-operand = 16 batches' h (LDS,
// 512B rows, 16B slots XOR-swizzled by (row&7)). Layouts as validated in v3:
//   A: lane holds A[RT + (lane&15)][ks*32 + (lane>>4)*8 + i]
//   B: lane holds B[ks*32 + (lane>>4)*8 + i][lane&15]  (Bbuf row = batch)
//   D: lane holds D[RT + 4*(lane>>4) + r][lane&15]
__global__ __launch_bounds__(512, 2) void scan_mfma(
    const _Float16* __restrict__ xw,    // [B][Tc][H] f16 (bias included)
    const _Float16* __restrict__ Whh,   // [256][256] f16
    _Float16* __restrict__ carry,       // [B][H]
    _Float16* __restrict__ outh,        // [B][Tc][H] f16
    int Tc)
{
    const int tid  = threadIdx.x;
    const int wv   = tid >> 6;
    const int lane = tid & 63;
    const int col  = lane & 15;         // D-col (batch) == A-row-in-tile
    const int g    = lane >> 4;
    const int b0   = blockIdx.x * NB;
    const int R0   = wv * (NTILE * 16);
    const int swz  = (col & 7) << 4;

    // A fragments: 2 tiles x 8 k-slices x 4 VGPRs = 64 regs, loaded once.
    f16x8 A[NTILE][8];
#pragma unroll
    for (int tt = 0; tt < NTILE; ++tt)
#pragma unroll
        for (int ks = 0; ks < 8; ++ks)
            A[tt][ks] = *(const f16x8*)(Whh + (long)(R0 + tt * 16 + col) * H_ + ks * 32 + g * 8);

    __shared__ __align__(16) _Float16 Bbuf[2][16][256]; // 16KB, swizzled slots

    // init Bbuf[0] from carry: 512 thr = 16 rows x 32 slots
    {
        const int rr = tid >> 5, s = tid & 31;
        uint4 v = *(const uint4*)(carry + (long)(b0 + rr) * H_ + s * 8);
        *(uint4*)((char*)Bbuf + rr * 512 + (((s ^ (rr & 7))) << 4)) = v;
    }
    __syncthreads();

    const long xrow = (long)(b0 + col) * Tc;   // in steps
    uint2 pend[NTILE];

#pragma unroll 1
    for (int it = 0; it < Tc; ++it) {
        const int p = it & 1;

        // delayed global store of step it-1 (retires under this step's MFMAs)
        if (it > 0) {
#pragma unroll
            for (int tt = 0; tt < NTILE; ++tt)
                *(uint2*)(outh + (xrow + (it - 1)) * H_ + R0 + tt * 16 + 4 * g) = pend[tt];
        }

        // prefetch xw for this step (8B/lane/tile), consumed in epilogue
        uint2 xwp[NTILE];
#pragma unroll
        for (int tt = 0; tt < NTILE; ++tt)
            xwp[tt] = *(const uint2*)(xw + (xrow + it) * H_ + R0 + tt * 16 + 4 * g);

        // MFMA block: 8 k-slices, B-frag shared across tiles
        f32x4 acc[NTILE];
#pragma unroll
        for (int tt = 0; tt < NTILE; ++tt) acc[tt] = (f32x4){0.f, 0.f, 0.f, 0.f};
        const char* rb = (const char*)Bbuf + (p * 16 + col) * 512;
#pragma unroll
        for (int ks = 0; ks < 8; ++ks) {
            f16x8 bf = *(const f16x8*)(rb + (((ks * 4 + g) << 4) ^ swz));
#pragma unroll
            for (int tt = 0; tt < NTILE; ++tt)
                acc[tt] = __builtin_amdgcn_mfma_f32_16x16x32_f16(A[tt][ks], bf, acc[tt], 0, 0, 0);
        }

        // epilogue: tanh + pack, write h to Bbuf[p^1] (keep for global next it)
        char* wb = (char*)Bbuf + ((p ^ 1) * 16 + col) * 512;
#pragma unroll
        for (int tt = 0; tt < NTILE; ++tt) {
            const int j0 = R0 + tt * 16 + 4 * g;
            union { uint2 u; _Float16 h4[4]; } xv; xv.u = xwp[tt];
            union { _Float16 h4[4]; uint2 u; } pk;
#pragma unroll
            for (int r = 0; r < 4; ++r)
                pk.h4[r] = (_Float16)fast_tanh(acc[tt][r] + (float)xv.h4[r]);
            *(uint2*)(wb + (((j0 >> 3) << 4) ^ swz) + ((j0 << 1) & 15)) = pk.u;
            pend[tt] = pk.u;
        }
        __syncthreads();
    }

    // final step's global store + carry out
#pragma unroll
    for (int tt = 0; tt < NTILE; ++tt) {
        const int j0 = R0 + tt * 16 + 4 * g;
        *(uint2*)(outh + (xrow + (Tc - 1)) * H_ + j0) = pend[tt];
        *(uint2*)(carry + (long)(b0 + col) * H_ + j0) = pend[tt];
    }
}

// ---- transpose: tmp [b][tc][j] f16 -> out [b][j][t0+tc] (bf16|f32) -------
__global__ __launch_bounds__(256, 1) void transpose_out(
    const _Float16* __restrict__ tmp, void* __restrict__ out,
    const int* __restrict__ flag, int t0, int Tc)
{
    const int nTc = (Tc + 63) >> 6;
    int bid = blockIdx.x;
    const int jblk = bid & 3; bid >>= 2;           // H_/64 == 4
    const int tcblk = bid % nTc;
    const int b = bid / nTc;
    const bool f32o = (*flag != 0);
    const int tid = threadIdx.x;

    __shared__ float tile[64][65];                 // 65: conflict-free both axes
#pragma unroll
    for (int k = 0; k < 16; ++k) {
        int idx = k * 256 + tid;
        int r = idx >> 6, c = idx & 63;
        int tc = tcblk * 64 + r;
        tile[r][c] = (tc < Tc)
            ? (float)tmp[((long)b * Tc + tc) * H_ + jblk * 64 + c] : 0.f;
    }
    __syncthreads();
#pragma unroll
    for (int k = 0; k < 16; ++k) {
        int idx = k * 256 + tid;
        int jr = idx >> 6, tc = idx & 63;
        if (tcblk * 64 + tc < Tc) {
            float v = tile[tc][jr];
            long o = ((long)b * H_ + jblk * 64 + jr) * (long)T_ + t0 + tcblk * 64 + tc;
            if (f32o) ((float*)out)[o] = v;
            else      ((__hip_bfloat16*)out)[o] = __float2bfloat16(v);
        }
    }
}

// ---------------------------------------------------------------------------
extern "C" void kernel_launch(void* const* d_in, const int* in_sizes, int n_in,
                              void* d_out, int out_size, void* d_ws, size_t ws_size,
                              hipStream_t stream) {
    const void* x    = d_in[0];
    const void* wih0 = d_in[1];
    const void* whh0 = d_in[2];
    const void* bih0 = d_in[3];
    const void* bhh0 = d_in[4];
    const void* wih1 = d_in[5];
    const void* whh1 = d_in[6];
    const void* bih1 = d_in[7];
    const void* bhh1 = d_in[8];
    (void)in_sizes; (void)n_in; (void)out_size;

    char* ws = (char*)d_ws;
    size_t off = 0;
    auto alloc = [&](size_t bytes) -> void* {
        void* p = ws + off;
        off += (bytes + 255) & ~(size_t)255;
        return p;
    };

    int*      flag    = (int*)alloc(256);
    _Float16* wih0_16 = (_Float16*)alloc((size_t)H_ * D_ * 2);
    _Float16* whh0_16 = (_Float16*)alloc((size_t)H_ * H_ * 2);
    _Float16* wih1_16 = (_Float16*)alloc((size_t)H_ * H_ * 2);
    _Float16* whh1_16 = (_Float16*)alloc((size_t)H_ * H_ * 2);
    float*    bias0   = (float*)alloc(H_ * 4);
    float*    bias1   = (float*)alloc(H_ * 4);
    _Float16* carry0  = (_Float16*)alloc((size_t)B_ * H_ * 2);
    _Float16* carry1  = (_Float16*)alloc((size_t)B_ * H_ * 2);
    size_t fixed = off;

    // largest chunk Tc (<=256) whose two chunk buffers (xwc + h0c) fit in ws
    int Tc = 256;
    while (Tc > 16 && fixed + 2 * ((size_t)B_ * Tc * H_ * 2 + 256) > ws_size) Tc >>= 1;
    _Float16* xwc = (_Float16*)alloc((size_t)B_ * Tc * H_ * 2);
    _Float16* h0c = (_Float16*)alloc((size_t)B_ * Tc * H_ * 2);

    detect_dtype<<<1, 64, 0, stream>>>((const unsigned short*)whh0, flag);
    prep_w<<<(H_ * H_ + 255) / 256, 256, 0, stream>>>(
        wih0, whh0, bih0, bhh0, wih1, whh1, bih1, bhh1,
        wih0_16, whh0_16, wih1_16, whh1_16, bias0, bias1, (uint4*)carry0, flag);

    const int nproj = (B_ * Tc) / 16;
    const int nTc   = (Tc + 63) / 64;
    for (int t0 = 0; t0 < T_; t0 += Tc) {
        proj_chunk<D_, true><<<nproj, 256, 0, stream>>>(x, wih0_16, bias0, xwc, flag, t0, Tc);
        scan_mfma<<<B_ / NB, 512, 0, stream>>>(xwc, whh0_16, carry0, h0c, Tc);
        proj_chunk<H_, false><<<nproj, 256, 0, stream>>>(h0c, wih1_16, bias1, xwc, flag, t0, Tc);
        scan_mfma<<<B_ / NB, 512, 0, stream>>>(xwc, whh1_16, carry1, h0c, Tc);
        transpose_out<<<B_ * nTc * (H_ / 64), 256, 0, stream>>>(h0c, d_out, flag, t0, Tc);
    }
}